// Round 20
// baseline (171.718 us; speedup 1.0000x reference)
//
#include <hip/hip_runtime.h>

// PartialGConv: partial temporal conv (TK=9, pad 4) + mask-ratio + graph einsum.
// FUSED kernel (r19 structure): bf16 implicit-GEMM (MFMA 16x16x32, BM=192 x
// BN=112(4t, 100 useful) x K=576), once-staged B window, 2-buffer LDS A-ring,
// prologue-staged misc, m_bool overlapped with K-loop, single-pass Pl
// contraction, bijective XCD swizzle, 2 blocks/CU.
// r20: K-loop is LDS-READ-BW bound (52KB/step ~= measured 1320cy/step at
// 85B/cy). Wave tiles 48x64 acc[3][4] -> 64x64 acc[4][4]: 6 waves (384thr,
// 3Mx2N), per-step reads 52->45KB (-13.5%), same MFMA count in deeper
// clusters. Fragment layouts/swizzles unchanged.
//
// ws layout (bytes):
//   xmr  u16[32][6656][64]  @0          x*mask bf16 row-major, padded rows
//   wb   u16[192][576]      @27,262,976 weights bf16, k=dt*64+cin, 16B-slot swizzled
//   msum f32[32][6400]      @27,484,160 sum_cin mask
//   s    f32[32][6400]      @28,303,360 576/(upd+eps)*uc^2
//   mr   f32[32][6400]      @29,122,560 mask_ratio
//   mb   f32[32][6400]      @29,941,760 m_bool
//   Bc   f32[32][3][256][25]@30,760,960 sum_v uc*A[k,v,w]

typedef unsigned short u16;
typedef unsigned int u32;
typedef short short8 __attribute__((ext_vector_type(8)));
typedef float f32x4 __attribute__((ext_vector_type(4)));

#define TV 6400
#define KC 192
#define KDIM 576
#define NPADT 6656          // 100 front pad + 6400 + 156 back pad
#define Y_SIZE 13107200
#define MB_OFF 13109075     // Y_SIZE + 1875

#define OFF_WB   27262976
#define OFF_MSUM 27484160
#define OFF_S    28303360
#define OFF_MR   29122560
#define OFF_MB   29941760
#define OFF_BC   30760960

// LDS map (73,824 B total -> 2 blocks/CU). K-loop: xwin [0,39936) =
// 312 rows x 128B; A-ring [39936,64512) = 2 x 12,288.
// Misc (PROLOGUE-staged, never aliased): Ab @64512 (6144) | Bcs @70656 (1200)
// | mrs @71856 (400) | bias @72256 (768) | ss @73024 (400) | mbs @73424 (400).
// Epilogue aliases: Pl u16[192][168] @0 (64,512); Ys f32[32][104] @0.
#define L_ARING 39936
#define L_AB    64512
#define L_BCS   70656
#define L_MRS   71856
#define L_BIAS  72256
#define L_SS    73024
#define L_MBS   73424

#define VMCNT(N) asm volatile("s_waitcnt vmcnt(" #N ")" ::: "memory")

__device__ __forceinline__ u16 f2bf(float f) {
  u32 u = __builtin_bit_cast(u32, f);
  u = (u + 0x7FFFu + ((u >> 16) & 1u)) >> 16;   // RTNE
  return (u16)u;
}
__device__ __forceinline__ float bf2f(u16 h) {
  return __builtin_bit_cast(float, (u32)h << 16);
}
__device__ __forceinline__ void gload_lds16(const u16* g, u16* l) {
  __builtin_amdgcn_global_load_lds(
      (const __attribute__((address_space(1))) u32*)(const void*)g,
      (__attribute__((address_space(3))) u32*)(void*)l, 16, 0, 0);
}

// ---- xmr = bf16(x*mask) row-major [tvp][64] + msum; pads via extra blocks ---
__global__ void k_xmT(const float* __restrict__ x, const float* __restrict__ mask,
                      u16* __restrict__ xmr, float* __restrict__ msum) {
  const int tvb = blockIdx.x, n = blockIdx.y;   // grid (104, 32), block 256
  if (tvb >= 100) {                             // pad blocks: zero 256 pad rows
    for (int j = (tvb - 100) * 256 + threadIdx.x; j < 2048; j += 1024) {
      int row = j >> 3, c = j & 7;              // 256 rows x 8 uint4
      int tvrow = (row < 100) ? row : (6400 + row);
      uint4 z; z.x = z.y = z.z = z.w = 0u;
      *(uint4*)(xmr + ((size_t)n * NPADT + tvrow) * 64 + c * 8) = z;
    }
    return;
  }
  const int tvl = threadIdx.x & 63, q = threadIdx.x >> 6;  // 4 quads of 16 cin
  const int tv = tvb * 64 + tvl;
  const float* xp = x + ((size_t)n * 64 + q * 16) * TV + tv;
  const float* mp = mask + ((size_t)n * 64 + q * 16) * TV + tv;
  u16 vals[16];
  float msacc = 0.f;
#pragma unroll
  for (int j = 0; j < 16; ++j) {                // coalesced: lanes = consecutive tv
    float xv = xp[(size_t)j * TV];
    float mv = mp[(size_t)j * TV];
    msacc += mv;
    vals[j] = f2bf(xv * mv);
  }
  uint4 lo, hi;
  lo.x = vals[0] | ((u32)vals[1] << 16);  lo.y = vals[2] | ((u32)vals[3] << 16);
  lo.z = vals[4] | ((u32)vals[5] << 16);  lo.w = vals[6] | ((u32)vals[7] << 16);
  hi.x = vals[8] | ((u32)vals[9] << 16);  hi.y = vals[10] | ((u32)vals[11] << 16);
  hi.z = vals[12] | ((u32)vals[13] << 16); hi.w = vals[14] | ((u32)vals[15] << 16);
  u16* dst = xmr + ((size_t)n * NPADT + 100 + tv) * 64 + q * 16;
  *(uint4*)dst = lo;
  *(uint4*)(dst + 8) = hi;
  __shared__ float red[4][64];
  red[q][tvl] = msacc;
  __syncthreads();
  if (q == 0) msum[n * TV + tv] = red[0][tvl] + red[1][tvl] + red[2][tvl] + red[3][tvl];
}

// ---- wb[kc][k=dt*64+cin], bf16, 16B-slot XOR pre-swizzle (by (kc>>1)&3) -----
__global__ void k_w(const float* __restrict__ weight, u16* __restrict__ wb) {
  int i = blockIdx.x * 256 + threadIdx.x;      // 110592
  if (i >= 110592) return;
  int kc = i / KDIM, k = i % KDIM;
  int cin = k & 63, dt = k >> 6;
  float v = weight[(kc * 64 + cin) * 9 + dt];
  int phys = (k & ~31) | ((((k >> 3) & 3) ^ ((kc >> 1) & 3)) << 3) | (k & 7);
  wb[kc * KDIM + phys] = f2bf(v);
}

// ---- per (n, t-pair): upd -> s, mask_ratio, m_bool, Bc ----------------------
// 2 t per 64-thread block: lanes 0-24 -> t0, lanes 32-56 -> t1.
__global__ void k_prep(const float* __restrict__ msum, const float* __restrict__ A_g,
                       float* __restrict__ s_ws, float* __restrict__ mr_ws,
                       float* __restrict__ mb_ws, float* __restrict__ Bc_ws) {
  int b = blockIdx.x;                          // 4096 = n*128 + tp
  int n = b >> 7, tp = b & 127;
  int tid = threadIdx.x;                       // 64
  int half = tid >> 5, l = tid & 31;
  int t = tp * 2 + half;
  __shared__ float uc[2][25];
  if (l < 25) {
    float upd = 0.f;
    for (int dt = 0; dt < 9; ++dt) {
      int tt = t + dt - 4;
      if (tt >= 0 && tt < 256) upd += msum[n * TV + tt * 25 + l];
    }
    float u_c = fminf(fmaxf(upd, 0.f), 1.f);
    float ratio = 576.f / (upd + 1e-8f);
    s_ws[n * TV + t * 25 + l] = ratio * u_c * u_c;  // coeff of raw in out
    uc[half][l] = u_c;
  }
  __syncthreads();
  if (l < 25) {
    int w = l;
    float M = 0.f;
    for (int k = 0; k < 3; ++k) {
      float acc = 0.f;
      for (int v = 0; v < 25; ++v) acc += uc[half][v] * A_g[(k * 25 + v) * 25 + w];
      Bc_ws[((size_t)(n * 3 + k) * 256 + t) * 25 + w] = acc;
      M += acc;
    }
    float mbv = (M != 0.f) ? 1.f : 0.f;
    mr_ws[n * TV + t * 25 + w] = mbv / (M + 1e-8f);
    mb_ws[n * TV + t * 25 + w] = mbv;
  }
}

// ---- FUSED: implicit-GEMM + MFMA (k,v)-contraction + coalesced epilogue -----
// Block (tg, n) via bijective XCD swizzle. 384 threads, 6 waves = 3(M) x 2(N),
// wave tile 64x64 (acc[4][4]; wn=1 -> 64x48, acc[4][3]). 2-buffer A-ring;
// prologue-staged misc; m_bool overlapped; single-pass Pl contraction.
__global__ __launch_bounds__(384, 3) void k_fused(
    const u16* __restrict__ xmr, const u16* __restrict__ wb,
    const float* __restrict__ s_g, const float* __restrict__ A_g,
    const float* __restrict__ Bc_g, const float* __restrict__ mr_g,
    const float* __restrict__ mb_g, const float* __restrict__ bias_g,
    float* __restrict__ out) {
  __shared__ __align__(16) char ring[73824];

  const int tid = threadIdx.x;
  // XCD swizzle: nwg = 2048 = 8 XCDs x 256; bijective since 2048 % 8 == 0.
  const int flat = blockIdx.y * 64 + blockIdx.x;
  const int swz = (flat & 7) * 256 + (flat >> 3);
  const int tg = swz & 63;                    // 0..63 (4-t group)
  const int n = swz >> 6;                     // 0..31
  const int T = tg * 100;                     // window start (padded coords)
  const int lane = tid & 63, wid = tid >> 6;  // wid 0..5
  const int wm = wid >> 1, wn = wid & 1;      // 3 M-groups of 64 rows, 2 N-groups
  const int lrow = lane & 15, lgrp = lane >> 4;
  const int nf = 4 - wn, colb = wn * 64;

  const u16* xmn = xmr + (size_t)n * NPADT * 64;
  u16* xwin = (u16*)(ring);
  u16*   Abu   = (u16*)(ring + L_AB);  // [3k][2nt][16w][32v] bf16 B-frag layout
  float* Bcsf  = (float*)(ring + L_BCS);
  float* mrsf  = (float*)(ring + L_MRS);
  float* biasf = (float*)(ring + L_BIAS);
  float* ssf   = (float*)(ring + L_SS);
  float* mbsf  = (float*)(ring + L_MBS);

  f32x4 acc[4][4] = {};

  // A staging helper: 12 tile-loads spread over 6 waves (2 each).
  auto stageA = [&](int buf, int ks) {
    u16* abase = (u16*)(ring + L_ARING + buf * 12288);
#pragma unroll
    for (int j = 0; j < 2; ++j) {
      int task = wid + j * 6;
      const u16* src = wb + (size_t)(task * 16 + (lane >> 2)) * KDIM + ks * 32 + (lane & 3) * 8;
      gload_lds16(src, abase + task * 512);
    }
  };

  // ---- prologue: B window (39 gloads) + A(0) + ALL epilogue misc ------------
  {
    // LDS[row][slot] = global[row][slot ^ (row&7)] in WINDOW coords.
    const int srow_g = lane >> 3, sl = (lane & 7) ^ (lane >> 3);  // per-lane
    for (int t = wid; t < 39; t += 6) {
      const u16* src = xmn + ((size_t)(T + t * 8 + srow_g) * 64 + sl * 8);
      gload_lds16(src, xwin + t * 512);
    }
    stageA(0, 0);
    // misc: latency hides under the window gloads above
    for (int i = tid; i < 3072; i += 384) {
      int kk = i >> 10, r = i & 1023;
      int nt = r >> 9, rr = r & 511, wl = rr >> 5, v = rr & 31;
      int w = nt * 16 + wl;
      float val = (v < 25 && w < 25) ? A_g[(kk * 25 + v) * 25 + w] : 0.f;
      Abu[i] = f2bf(val);
    }
    if (tid < 300) {
      int k = tid / 100, t = (tid % 100) / 25, w = tid % 25;
      Bcsf[tid] = Bc_g[((size_t)(n * 3 + k) * 256 + tg * 4 + t) * 25 + w];
    }
    if (tid < 100) {
      mrsf[tid] = mr_g[n * TV + T + tid];
      ssf[tid]  = s_g[n * TV + T + tid];
      mbsf[tid] = mb_g[n * TV + T + tid];
    }
    if (tid >= 192) biasf[tid - 192] = bias_g[tid - 192];
  }
  __syncthreads();                     // drains vmcnt+lgkmcnt: gloads + ds_writes

  const size_t base_n = (size_t)(n * 64) * 6400 + T;

  // m_bool: c-independent broadcast; issued HERE so the 52MB chip-wide write
  // drains under the K-loop (one-time retire wait at step-0's VMCNT(0)).
  for (int i = tid; i < 6400; i += 384) {
    int cc = i / 100, j = i % 100;
    out[MB_OFF + base_n + (size_t)cc * 6400 + j] = mbsf[j];
  }

  // ---- K-loop: 18 steps; 2-buffer A-ring, 1 drain+barrier per step ----------
  for (int ks = 0; ks < 18; ++ks) {
    const int cur = ks & 1;
    if (ks < 17) stageA(cur ^ 1, ks + 1);

    const u16* abuf = (const u16*)(ring + L_ARING + cur * 12288);
    short8 af[4];
#pragma unroll
    for (int m = 0; m < 4; ++m) {
      int arow = wm * 64 + m * 16 + lrow;
      af[m] = *(const short8*)&abuf[arow * 32 + ((lgrp ^ ((arow >> 1) & 3)) << 3)];
    }
    const int dt = ks >> 1;
    const int rbase = 100 + (dt - 4) * 25 + colb + lrow;   // window row for ct=0
    const int slb = (ks & 1) * 4 + lgrp;                   // logical 16B slot
#pragma unroll
    for (int ct = 0; ct < 4; ++ct) {
      if (ct < nf) {
        int srow = rbase + ct * 16;
        short8 bfr = *(const short8*)&xwin[srow * 64 + ((slb ^ (srow & 7)) << 3)];
#pragma unroll
        for (int m = 0; m < 4; ++m)
          acc[m][ct] = __builtin_amdgcn_mfma_f32_16x16x32_bf16(af[m], bfr, acc[m][ct], 0, 0, 0);
      }
    }

    if (ks < 17) {
      VMCNT(0);                        // own A(ks+1) loads landed
      __builtin_amdgcn_s_barrier();    // all waves done reading abuf[cur]
      asm volatile("" ::: "memory");
    }
  }

  // ---- epilogue: single-pass Pl[192][168] (aliases xwin+A-ring) ------------
  __syncthreads();                     // all xwin/abuf reads done; safe to alias
  u16* Plu = (u16*)ring;               // [192][168]: row = kc, tcol = t*40+v
  {
    uint4 z; z.x = z.y = z.z = z.w = 0u;
    for (int i = tid; i < 4032; i += 384) ((uint4*)ring)[i] = z;  // zero 64.5KB
  }
  __syncthreads();

  // P-stage: ALL kc rows at once (no k-guard, no divergence)
#pragma unroll
  for (int m = 0; m < 4; ++m) {
    int R = wm * 64 + m * 16 + lgrp * 4;       // global kc row base
#pragma unroll
    for (int ct = 0; ct < 4; ++ct) {
      if (ct < nf) {
        int col = colb + ct * 16 + lrow;
        if (col < 100) {
          int t = col / 25, v = col - t * 25;
          float sv = ssf[col];
          int tc = t * 40 + v;
#pragma unroll
          for (int r = 0; r < 4; ++r)
            Plu[(R + r) * 168 + tc] = f2bf(acc[m][ct][r] * sv);
        }
      }
    }
  }
  __syncthreads();

  // contraction: y(ct,w) = sum_{k,v} P * A — M-tiles mt = wid*3 + mi (16 total)
  f32x4 yacc[3][2] = {};
#pragma unroll
  for (int k = 0; k < 3; ++k) {
    short8 pb[2];
#pragma unroll
    for (int nt = 0; nt < 2; ++nt)
      pb[nt] = *(const short8*)&Abu[((k * 2 + nt) * 16 + lrow) * 32 + lgrp * 8];
#pragma unroll
    for (int mi = 0; mi < 3; ++mi) {
      int mt = wid * 3 + mi;
      if (mt < 16) {
        // pa row = k*64 + c-local (mt*4 + lrow>>2); k-dim = t*40 + v
        const short8 pa = *(const short8*)
            &Plu[(k * 64 + mt * 4 + (lrow >> 2)) * 168 + (lrow & 3) * 40 + lgrp * 8];
#pragma unroll
        for (int nt = 0; nt < 2; ++nt)
          yacc[mi][nt] = __builtin_amdgcn_mfma_f32_16x16x32_bf16(pa, pb[nt], yacc[mi][nt], 0, 0, 0);
      }
    }
  }

  // ---- finalize + transposed coalesced y writes ----------------------------
  // yacc[mi][nt][r]: mt = wid*3+mi; ct-row = mt*16 + lgrp*4 + r ->
  // c = mt*4 + lgrp, t = r; col w = nt*16 + lrow.
  float (*Ysf)[104] = (float(*)[104])ring;     // aliases Pl, barrier-separated
#pragma unroll
  for (int half = 0; half < 2; ++half) {
    __syncthreads();                   // contraction Pl reads / prior Ys done
#pragma unroll
    for (int mi = 0; mi < 3; ++mi) {
      int mt = wid * 3 + mi;
      if (mt < 16 && (mt >> 3) == half) {
        int c = mt * 4 + lgrp;                 // 0..63
#pragma unroll
        for (int nt = 0; nt < 2; ++nt) {
          int w = nt * 16 + lrow;
          if (w < 25) {
#pragma unroll
            for (int r = 0; r < 4; ++r) {
              float bt = biasf[c] * Bcsf[r * 25 + w] +
                         biasf[64 + c] * Bcsf[100 + r * 25 + w] +
                         biasf[128 + c] * Bcsf[200 + r * 25 + w];
              Ysf[c & 31][r * 25 + w] = (yacc[mi][nt][r] + bt) * mrsf[r * 25 + w];
            }
          }
        }
      }
    }
    __syncthreads();
    for (int i = tid; i < 3200; i += 384) {
      int ch = i / 100, j = i % 100;
      out[base_n + (size_t)(half * 32 + ch) * 6400 + j] = Ysf[ch][j];
    }
  }
}

extern "C" void kernel_launch(void* const* d_in, const int* in_sizes, int n_in,
                              void* d_out, int out_size, void* d_ws, size_t ws_size,
                              hipStream_t stream) {
  const float* x      = (const float*)d_in[0];
  const float* A      = (const float*)d_in[1];
  const float* mask   = (const float*)d_in[2];
  const float* weight = (const float*)d_in[3];
  const float* bias   = (const float*)d_in[4];
  float* out = (float*)d_out;
  char* ws = (char*)d_ws;

  u16*   xmr   = (u16*)(ws);
  u16*   wb    = (u16*)(ws + OFF_WB);
  float* msum  = (float*)(ws + OFF_MSUM);
  float* s_ws  = (float*)(ws + OFF_S);
  float* mr_ws = (float*)(ws + OFF_MR);
  float* mb_ws = (float*)(ws + OFF_MB);
  float* Bc_ws = (float*)(ws + OFF_BC);

  k_xmT<<<dim3(104, 32), 256, 0, stream>>>(x, mask, xmr, msum);
  k_w<<<432, 256, 0, stream>>>(weight, wb);
  k_prep<<<4096, 64, 0, stream>>>(msum, A, s_ws, mr_ws, mb_ws, Bc_ws);

  hipMemcpyAsync(out + Y_SIZE, A, 1875 * sizeof(float),
                 hipMemcpyDeviceToDevice, stream);

  k_fused<<<dim3(64, 32), 384, 0, stream>>>(xmr, wb, s_ws, A, Bc_ws, mr_ws,
                                            mb_ws, bias, out);
}

// Round 21
// 115.652 us; speedup vs baseline: 1.4848x; 1.4848x over previous
//
#include <hip/hip_runtime.h>

// PartialGConv: partial temporal conv (TK=9, pad 4) + mask-ratio + graph einsum.
// FUSED kernel (r19, BEST measured: 115.9us total, k_fused 87.5us):
// bf16 implicit-GEMM (MFMA 16x16x32, BM=192 x BN=112(4t, 100 useful) x K=576),
// once-staged B window, 2-buffer LDS A-ring, prologue-staged epilogue misc,
// m_bool overlapped with K-loop, single-pass Pl[192][168] MFMA contraction,
// bijective XCD swizzle, 512 thr / 8 waves, 2 blocks/CU.
// r21 = exact revert of r20's 64x64-tile regression (occupancy halved).
//
// Structural floor analysis: K-loop is LDS-read-BW bound (52KB/step/block ~=
// 620cy at 85B/cy/CU, x2 resident blocks ~= 1240cy/step; measured ~1320).
// Schedule variants (barrier domains, counted vmcnt, zero-barrier, reg-
// pipeline) all null/negative; wins came from layout/locality/work-reduction.
//
// ws layout (bytes):
//   xmr  u16[32][6656][64]  @0          x*mask bf16 row-major, padded rows
//   wb   u16[192][576]      @27,262,976 weights bf16, k=dt*64+cin, 16B-slot swizzled
//   msum f32[32][6400]      @27,484,160 sum_cin mask
//   s    f32[32][6400]      @28,303,360 576/(upd+eps)*uc^2
//   mr   f32[32][6400]      @29,122,560 mask_ratio
//   mb   f32[32][6400]      @29,941,760 m_bool
//   Bc   f32[32][3][256][25]@30,760,960 sum_v uc*A[k,v,w]

typedef unsigned short u16;
typedef unsigned int u32;
typedef short short8 __attribute__((ext_vector_type(8)));
typedef float f32x4 __attribute__((ext_vector_type(4)));

#define TV 6400
#define KC 192
#define KDIM 576
#define NPADT 6656          // 100 front pad + 6400 + 156 back pad
#define Y_SIZE 13107200
#define MB_OFF 13109075     // Y_SIZE + 1875

#define OFF_WB   27262976
#define OFF_MSUM 27484160
#define OFF_S    28303360
#define OFF_MR   29122560
#define OFF_MB   29941760
#define OFF_BC   30760960

// LDS map (73,824 B total -> 2 blocks/CU). K-loop: xwin [0,39936) =
// 312 rows x 128B; A-ring [39936,64512) = 2 x 12,288.
// Misc (PROLOGUE-staged, never aliased): Ab @64512 (6144) | Bcs @70656 (1200)
// | mrs @71856 (400) | bias @72256 (768) | ss @73024 (400) | mbs @73424 (400).
// Epilogue aliases: Pl u16[192][168] @0 (64,512); Ys f32[32][104] @0.
#define L_ARING 39936
#define L_AB    64512
#define L_BCS   70656
#define L_MRS   71856
#define L_BIAS  72256
#define L_SS    73024
#define L_MBS   73424

#define VMCNT(N) asm volatile("s_waitcnt vmcnt(" #N ")" ::: "memory")

__device__ __forceinline__ u16 f2bf(float f) {
  u32 u = __builtin_bit_cast(u32, f);
  u = (u + 0x7FFFu + ((u >> 16) & 1u)) >> 16;   // RTNE
  return (u16)u;
}
__device__ __forceinline__ float bf2f(u16 h) {
  return __builtin_bit_cast(float, (u32)h << 16);
}
__device__ __forceinline__ void gload_lds16(const u16* g, u16* l) {
  __builtin_amdgcn_global_load_lds(
      (const __attribute__((address_space(1))) u32*)(const void*)g,
      (__attribute__((address_space(3))) u32*)(void*)l, 16, 0, 0);
}

// ---- xmr = bf16(x*mask) row-major [tvp][64] + msum; pads via extra blocks ---
__global__ void k_xmT(const float* __restrict__ x, const float* __restrict__ mask,
                      u16* __restrict__ xmr, float* __restrict__ msum) {
  const int tvb = blockIdx.x, n = blockIdx.y;   // grid (104, 32), block 256
  if (tvb >= 100) {                             // pad blocks: zero 256 pad rows
    for (int j = (tvb - 100) * 256 + threadIdx.x; j < 2048; j += 1024) {
      int row = j >> 3, c = j & 7;              // 256 rows x 8 uint4
      int tvrow = (row < 100) ? row : (6400 + row);
      uint4 z; z.x = z.y = z.z = z.w = 0u;
      *(uint4*)(xmr + ((size_t)n * NPADT + tvrow) * 64 + c * 8) = z;
    }
    return;
  }
  const int tvl = threadIdx.x & 63, q = threadIdx.x >> 6;  // 4 quads of 16 cin
  const int tv = tvb * 64 + tvl;
  const float* xp = x + ((size_t)n * 64 + q * 16) * TV + tv;
  const float* mp = mask + ((size_t)n * 64 + q * 16) * TV + tv;
  u16 vals[16];
  float msacc = 0.f;
#pragma unroll
  for (int j = 0; j < 16; ++j) {                // coalesced: lanes = consecutive tv
    float xv = xp[(size_t)j * TV];
    float mv = mp[(size_t)j * TV];
    msacc += mv;
    vals[j] = f2bf(xv * mv);
  }
  uint4 lo, hi;
  lo.x = vals[0] | ((u32)vals[1] << 16);  lo.y = vals[2] | ((u32)vals[3] << 16);
  lo.z = vals[4] | ((u32)vals[5] << 16);  lo.w = vals[6] | ((u32)vals[7] << 16);
  hi.x = vals[8] | ((u32)vals[9] << 16);  hi.y = vals[10] | ((u32)vals[11] << 16);
  hi.z = vals[12] | ((u32)vals[13] << 16); hi.w = vals[14] | ((u32)vals[15] << 16);
  u16* dst = xmr + ((size_t)n * NPADT + 100 + tv) * 64 + q * 16;
  *(uint4*)dst = lo;
  *(uint4*)(dst + 8) = hi;
  __shared__ float red[4][64];
  red[q][tvl] = msacc;
  __syncthreads();
  if (q == 0) msum[n * TV + tv] = red[0][tvl] + red[1][tvl] + red[2][tvl] + red[3][tvl];
}

// ---- wb[kc][k=dt*64+cin], bf16, 16B-slot XOR pre-swizzle (by (kc>>1)&3) -----
__global__ void k_w(const float* __restrict__ weight, u16* __restrict__ wb) {
  int i = blockIdx.x * 256 + threadIdx.x;      // 110592
  if (i >= 110592) return;
  int kc = i / KDIM, k = i % KDIM;
  int cin = k & 63, dt = k >> 6;
  float v = weight[(kc * 64 + cin) * 9 + dt];
  int phys = (k & ~31) | ((((k >> 3) & 3) ^ ((kc >> 1) & 3)) << 3) | (k & 7);
  wb[kc * KDIM + phys] = f2bf(v);
}

// ---- per (n, t-pair): upd -> s, mask_ratio, m_bool, Bc ----------------------
// 2 t per 64-thread block: lanes 0-24 -> t0, lanes 32-56 -> t1.
__global__ void k_prep(const float* __restrict__ msum, const float* __restrict__ A_g,
                       float* __restrict__ s_ws, float* __restrict__ mr_ws,
                       float* __restrict__ mb_ws, float* __restrict__ Bc_ws) {
  int b = blockIdx.x;                          // 4096 = n*128 + tp
  int n = b >> 7, tp = b & 127;
  int tid = threadIdx.x;                       // 64
  int half = tid >> 5, l = tid & 31;
  int t = tp * 2 + half;
  __shared__ float uc[2][25];
  if (l < 25) {
    float upd = 0.f;
    for (int dt = 0; dt < 9; ++dt) {
      int tt = t + dt - 4;
      if (tt >= 0 && tt < 256) upd += msum[n * TV + tt * 25 + l];
    }
    float u_c = fminf(fmaxf(upd, 0.f), 1.f);
    float ratio = 576.f / (upd + 1e-8f);
    s_ws[n * TV + t * 25 + l] = ratio * u_c * u_c;  // coeff of raw in out
    uc[half][l] = u_c;
  }
  __syncthreads();
  if (l < 25) {
    int w = l;
    float M = 0.f;
    for (int k = 0; k < 3; ++k) {
      float acc = 0.f;
      for (int v = 0; v < 25; ++v) acc += uc[half][v] * A_g[(k * 25 + v) * 25 + w];
      Bc_ws[((size_t)(n * 3 + k) * 256 + t) * 25 + w] = acc;
      M += acc;
    }
    float mbv = (M != 0.f) ? 1.f : 0.f;
    mr_ws[n * TV + t * 25 + w] = mbv / (M + 1e-8f);
    mb_ws[n * TV + t * 25 + w] = mbv;
  }
}

// ---- FUSED: implicit-GEMM + MFMA (k,v)-contraction + coalesced epilogue -----
// Block (tg, n) via bijective XCD swizzle. 512 threads, 8 waves = 4(M) x 2(N);
// 2-buffer A-ring; prologue-staged misc; m_bool overlapped with K-loop;
// single-pass Pl[192][168] contraction.
__global__ __launch_bounds__(512, 4) void k_fused(
    const u16* __restrict__ xmr, const u16* __restrict__ wb,
    const float* __restrict__ s_g, const float* __restrict__ A_g,
    const float* __restrict__ Bc_g, const float* __restrict__ mr_g,
    const float* __restrict__ mb_g, const float* __restrict__ bias_g,
    float* __restrict__ out) {
  __shared__ __align__(16) char ring[73824];

  const int tid = threadIdx.x;
  // XCD swizzle: nwg = 2048 = 8 XCDs x 256; bijective since 2048 % 8 == 0.
  const int flat = blockIdx.y * 64 + blockIdx.x;
  const int swz = (flat & 7) * 256 + (flat >> 3);
  const int tg = swz & 63;                    // 0..63 (4-t group)
  const int n = swz >> 6;                     // 0..31
  const int T = tg * 100;                     // window start (padded coords)
  const int lane = tid & 63, wid = tid >> 6;
  const int wm = wid >> 1, wn = wid & 1;
  const int lrow = lane & 15, lgrp = lane >> 4;
  const int nf = 4 - wn, colb = wn * 64;

  const u16* xmn = xmr + (size_t)n * NPADT * 64;
  u16* xwin = (u16*)(ring);
  u16*   Abu   = (u16*)(ring + L_AB);  // [3k][2nt][16w][32v] bf16 B-frag layout
  float* Bcsf  = (float*)(ring + L_BCS);
  float* mrsf  = (float*)(ring + L_MRS);
  float* biasf = (float*)(ring + L_BIAS);
  float* ssf   = (float*)(ring + L_SS);
  float* mbsf  = (float*)(ring + L_MBS);

  f32x4 acc[3][4] = {};

  // A staging helper: 12 tile-loads spread as waves 0-3: 2, waves 4-7: 1.
  auto stageA = [&](int buf, int ks) {
    u16* abase = (u16*)(ring + L_ARING + buf * 12288);
#pragma unroll
    for (int j = 0; j < 2; ++j) {
      int task = wid + j * 8;
      if (task < 12) {
        const u16* src = wb + (size_t)(task * 16 + (lane >> 2)) * KDIM + ks * 32 + (lane & 3) * 8;
        gload_lds16(src, abase + task * 512);
      }
    }
  };

  // ---- prologue: B window (39 gloads) + A(0) + ALL epilogue misc ------------
  {
    // LDS[row][slot] = global[row][slot ^ (row&7)] in WINDOW coords.
    const int srow_g = lane >> 3, sl = (lane & 7) ^ (lane >> 3);  // per-lane
    for (int t = wid; t < 39; t += 8) {
      const u16* src = xmn + ((size_t)(T + t * 8 + srow_g) * 64 + sl * 8);
      gload_lds16(src, xwin + t * 512);
    }
    stageA(0, 0);
    // misc: latency hides under the window gloads above
    for (int i = tid; i < 3072; i += 512) {
      int kk = i >> 10, r = i & 1023;
      int nt = r >> 9, rr = r & 511, wl = rr >> 5, v = rr & 31;
      int w = nt * 16 + wl;
      float val = (v < 25 && w < 25) ? A_g[(kk * 25 + v) * 25 + w] : 0.f;
      Abu[i] = f2bf(val);
    }
    if (tid < 300) {
      int k = tid / 100, t = (tid % 100) / 25, w = tid % 25;
      Bcsf[tid] = Bc_g[((size_t)(n * 3 + k) * 256 + tg * 4 + t) * 25 + w];
    }
    if (tid < 100) {
      mrsf[tid] = mr_g[n * TV + T + tid];
      ssf[tid]  = s_g[n * TV + T + tid];
      mbsf[tid] = mb_g[n * TV + T + tid];
    }
    if (tid >= 256 && tid < 448) biasf[tid - 256] = bias_g[tid - 256];
  }
  __syncthreads();                     // drains vmcnt+lgkmcnt: gloads + ds_writes

  const size_t base_n = (size_t)(n * 64) * 6400 + T;

  // m_bool: c-independent broadcast; issued HERE so the 52MB chip-wide write
  // drains under the K-loop (one-time retire wait at step-0's VMCNT(0)).
  for (int i = tid; i < 6400; i += 512) {
    int cc = i / 100, j = i % 100;
    out[MB_OFF + base_n + (size_t)cc * 6400 + j] = mbsf[j];
  }

  // ---- K-loop: 18 steps; 2-buffer A-ring, 1 drain+barrier per step ----------
  for (int ks = 0; ks < 18; ++ks) {
    const int cur = ks & 1;
    if (ks < 17) stageA(cur ^ 1, ks + 1);

    const u16* abuf = (const u16*)(ring + L_ARING + cur * 12288);
    short8 af[3];
#pragma unroll
    for (int m = 0; m < 3; ++m) {
      int arow = wm * 48 + m * 16 + lrow;
      af[m] = *(const short8*)&abuf[arow * 32 + ((lgrp ^ ((arow >> 1) & 3)) << 3)];
    }
    const int dt = ks >> 1;
    const int rbase = 100 + (dt - 4) * 25 + colb + lrow;   // window row for ct=0
    const int slb = (ks & 1) * 4 + lgrp;                   // logical 16B slot
#pragma unroll
    for (int ct = 0; ct < 4; ++ct) {
      if (ct < nf) {
        int srow = rbase + ct * 16;
        short8 bfr = *(const short8*)&xwin[srow * 64 + ((slb ^ (srow & 7)) << 3)];
#pragma unroll
        for (int m = 0; m < 3; ++m)
          acc[m][ct] = __builtin_amdgcn_mfma_f32_16x16x32_bf16(af[m], bfr, acc[m][ct], 0, 0, 0);
      }
    }

    if (ks < 17) {
      VMCNT(0);                        // own A(ks+1) loads landed
      __builtin_amdgcn_s_barrier();    // all waves done reading abuf[cur]
      asm volatile("" ::: "memory");
    }
  }

  // ---- epilogue: single-pass Pl[192][168] (aliases xwin+A-ring) ------------
  __syncthreads();                     // all xwin/abuf reads done; safe to alias
  u16* Plu = (u16*)ring;               // [192][168]: row = kc, tcol = t*40+v
  {
    uint4 z; z.x = z.y = z.z = z.w = 0u;
    for (int i = tid; i < 4032; i += 512) ((uint4*)ring)[i] = z;  // zero 64.5KB
  }
  __syncthreads();

  // P-stage: ALL kc rows at once (no k-guard, no divergence)
#pragma unroll
  for (int m = 0; m < 3; ++m) {
    int R = wm * 48 + m * 16 + lgrp * 4;       // global kc row base
#pragma unroll
    for (int ct = 0; ct < 4; ++ct) {
      if (ct < nf) {
        int col = colb + ct * 16 + lrow;
        if (col < 100) {
          int t = col / 25, v = col - t * 25;
          float sv = ssf[col];
          int tc = t * 40 + v;
#pragma unroll
          for (int r = 0; r < 4; ++r)
            Plu[(R + r) * 168 + tc] = f2bf(acc[m][ct][r] * sv);
        }
      }
    }
  }
  __syncthreads();

  // contraction: y(ct,w) = sum_{k,v} P * A — 12 clustered MFMAs per wave
  f32x4 yacc[2][2] = {};
#pragma unroll
  for (int k = 0; k < 3; ++k) {
    short8 pb[2];
#pragma unroll
    for (int nt = 0; nt < 2; ++nt)
      pb[nt] = *(const short8*)&Abu[((k * 2 + nt) * 16 + lrow) * 32 + lgrp * 8];
#pragma unroll
    for (int mi = 0; mi < 2; ++mi) {
      int mt = wid * 2 + mi;
      // pa row = k*64 + c-local (mt*4 + lrow>>2); k-dim = t*40 + v (lgrp*8..)
      const short8 pa = *(const short8*)
          &Plu[(k * 64 + mt * 4 + (lrow >> 2)) * 168 + (lrow & 3) * 40 + lgrp * 8];
#pragma unroll
      for (int nt = 0; nt < 2; ++nt)
        yacc[mi][nt] = __builtin_amdgcn_mfma_f32_16x16x32_bf16(pa, pb[nt], yacc[mi][nt], 0, 0, 0);
    }
  }

  // ---- finalize + transposed coalesced y writes ----------------------------
  // yacc[mi][nt][r]: ct = (wid*2+mi)*16 + lgrp*4 + r -> c = wid*8+mi*4+lgrp,
  // t = r; col w = nt*16 + lrow.
  float (*Ysf)[104] = (float(*)[104])ring;     // aliases Pl, barrier-separated
#pragma unroll
  for (int half = 0; half < 2; ++half) {
    __syncthreads();                   // contraction Pl reads / prior Ys done
    if ((wid >> 2) == half) {
#pragma unroll
      for (int mi = 0; mi < 2; ++mi) {
        int c = wid * 8 + mi * 4 + lgrp;       // 0..63
#pragma unroll
        for (int nt = 0; nt < 2; ++nt) {
          int w = nt * 16 + lrow;
          if (w < 25) {
#pragma unroll
            for (int r = 0; r < 4; ++r) {
              float bt = biasf[c] * Bcsf[r * 25 + w] +
                         biasf[64 + c] * Bcsf[100 + r * 25 + w] +
                         biasf[128 + c] * Bcsf[200 + r * 25 + w];
              Ysf[c & 31][r * 25 + w] = (yacc[mi][nt][r] + bt) * mrsf[r * 25 + w];
            }
          }
        }
      }
    }
    __syncthreads();
    for (int i = tid; i < 3200; i += 512) {
      int ch = i / 100, j = i % 100;
      out[base_n + (size_t)(half * 32 + ch) * 6400 + j] = Ysf[ch][j];
    }
  }
}

extern "C" void kernel_launch(void* const* d_in, const int* in_sizes, int n_in,
                              void* d_out, int out_size, void* d_ws, size_t ws_size,
                              hipStream_t stream) {
  const float* x      = (const float*)d_in[0];
  const float* A      = (const float*)d_in[1];
  const float* mask   = (const float*)d_in[2];
  const float* weight = (const float*)d_in[3];
  const float* bias   = (const float*)d_in[4];
  float* out = (float*)d_out;
  char* ws = (char*)d_ws;

  u16*   xmr   = (u16*)(ws);
  u16*   wb    = (u16*)(ws + OFF_WB);
  float* msum  = (float*)(ws + OFF_MSUM);
  float* s_ws  = (float*)(ws + OFF_S);
  float* mr_ws = (float*)(ws + OFF_MR);
  float* mb_ws = (float*)(ws + OFF_MB);
  float* Bc_ws = (float*)(ws + OFF_BC);

  k_xmT<<<dim3(104, 32), 256, 0, stream>>>(x, mask, xmr, msum);
  k_w<<<432, 256, 0, stream>>>(weight, wb);
  k_prep<<<4096, 64, 0, stream>>>(msum, A, s_ws, mr_ws, mb_ws, Bc_ws);

  hipMemcpyAsync(out + Y_SIZE, A, 1875 * sizeof(float),
                 hipMemcpyDeviceToDevice, stream);

  k_fused<<<dim3(64, 32), 512, 0, stream>>>(xmr, wb, s_ws, A, Bc_ws, mr_ws,
                                            mb_ws, bias, out);
}